// Round 1
// baseline (448.117 us; speedup 1.0000x reference)
//
#include <hip/hip_runtime.h>

#define EPSILON 0.1f
#define F_IN 256
#define F_OUT 96
#define NF 3
#define TCOLS 288  // NF * F_OUT, t row layout: [n][ii*96 + f]

// ---------------- histogram: edge counts per row ----------------
__global__ void hist_kernel(const int* __restrict__ row, int* __restrict__ cnt, int E) {
    int e = blockIdx.x * blockDim.x + threadIdx.x;
    if (e < E) atomicAdd(&cnt[row[e]], 1);
}

// ---------------- scan step 1: per-block (1024 elems) sums ----------------
__global__ __launch_bounds__(256) void scan_part(const int* __restrict__ cnt,
                                                 int* __restrict__ bsums, int N) {
    int i = blockIdx.x * 1024 + threadIdx.x * 4;
    int v = 0;
    if (i + 3 < N) {
        int4 q = *(const int4*)(cnt + i);
        v = q.x + q.y + q.z + q.w;
    } else {
        for (int j = 0; j < 4; ++j)
            if (i + j < N) v += cnt[i + j];
    }
    #pragma unroll
    for (int d = 32; d > 0; d >>= 1) v += __shfl_xor(v, d, 64);
    __shared__ int wsum[4];
    int lane = threadIdx.x & 63, wid = threadIdx.x >> 6;
    if (lane == 0) wsum[wid] = v;
    __syncthreads();
    if (threadIdx.x == 0) bsums[blockIdx.x] = wsum[0] + wsum[1] + wsum[2] + wsum[3];
}

// ---------------- scan step 2: exclusive scan of block sums (<=64 blocks) ----------------
__global__ void scan_sums(int* __restrict__ bsums, int* __restrict__ row_ptr,
                          int nb, int E, int N) {
    int lane = threadIdx.x;
    int v = (lane < nb) ? bsums[lane] : 0;
    int s = v;
    #pragma unroll
    for (int d = 1; d < 64; d <<= 1) {
        int o = __shfl_up(s, d, 64);
        if (lane >= d) s += o;
    }
    if (lane < nb) bsums[lane] = s - v;  // exclusive
    if (lane == 0) row_ptr[N] = E;
}

// ---------------- scan step 3: full exclusive scan, write row_ptr + offs ----------------
__global__ __launch_bounds__(256) void scan_write(const int* __restrict__ cnt,
                                                  const int* __restrict__ bsums,
                                                  int* __restrict__ row_ptr,
                                                  int* __restrict__ offs, int N) {
    int i = blockIdx.x * 1024 + threadIdx.x * 4;
    int q0 = 0, q1 = 0, q2 = 0, q3 = 0;
    if (i + 3 < N) {
        int4 q = *(const int4*)(cnt + i);
        q0 = q.x; q1 = q.y; q2 = q.z; q3 = q.w;
    } else {
        if (i     < N) q0 = cnt[i];
        if (i + 1 < N) q1 = cnt[i + 1];
        if (i + 2 < N) q2 = cnt[i + 2];
        if (i + 3 < N) q3 = cnt[i + 3];
    }
    int tsum = q0 + q1 + q2 + q3;
    int lane = threadIdx.x & 63, wid = threadIdx.x >> 6;
    int s = tsum;
    #pragma unroll
    for (int d = 1; d < 64; d <<= 1) {
        int o = __shfl_up(s, d, 64);
        if (lane >= d) s += o;
    }
    __shared__ int wsum[4];
    if (lane == 63) wsum[wid] = s;
    __syncthreads();
    int woff = 0;
    for (int w = 0; w < wid; ++w) woff += wsum[w];
    int e0 = bsums[blockIdx.x] + woff + (s - tsum);
    if (i     < N) { row_ptr[i]     = e0; offs[i]     = e0; } e0 += q0;
    if (i + 1 < N) { row_ptr[i + 1] = e0; offs[i + 1] = e0; } e0 += q1;
    if (i + 2 < N) { row_ptr[i + 2] = e0; offs[i + 2] = e0; } e0 += q2;
    if (i + 3 < N) { row_ptr[i + 3] = e0; offs[i + 3] = e0; }
}

// ---------------- scatter edges into CSR order ----------------
__global__ void scatter_kernel(const int* __restrict__ row, const int* __restrict__ col,
                               const float* __restrict__ vals, int* __restrict__ offs,
                               int* __restrict__ col_s, float* __restrict__ val_s, int E) {
    int e = blockIdx.x * blockDim.x + threadIdx.x;
    if (e < E) {
        int r = row[e];
        int p = atomicAdd(&offs[r], 1);
        col_s[p] = col[e];
        val_s[p] = vals[e];
    }
}

// ---------------- fused GEMM: t[n][ii*96+f] = dsc[ii][n] * (x @ W[ii])[n][f] ----------------
// block: 256 threads = 32(tx) x 8(ty); tile: BM=32 rows x 288 cols, BK=32
__global__ __launch_bounds__(256) void gemm_kernel(const float* __restrict__ x,
                                                   const float* __restrict__ w,
                                                   const float* __restrict__ dsc,
                                                   float* __restrict__ t, int N) {
    __shared__ float xs[32][33];          // +1 pad
    __shared__ float ws[32][TCOLS + 4];   // +4 pad breaks %32==0 stride

    int tid = threadIdx.x;
    int tx = tid & 31, ty = tid >> 5;
    int m0 = blockIdx.x * 32;

    float acc[4][9];
    #pragma unroll
    for (int i = 0; i < 4; ++i)
        #pragma unroll
        for (int j = 0; j < 9; ++j) acc[i][j] = 0.f;

    for (int k0 = 0; k0 < F_IN; k0 += 32) {
        // stage x tile: 32x32 floats, one float4 per thread
        {
            int r = tid >> 3;            // 0..31
            int kq = (tid & 7) * 4;      // 0..28
            float4 xv = make_float4(0.f, 0.f, 0.f, 0.f);
            if (m0 + r < N)
                xv = *(const float4*)(x + (size_t)(m0 + r) * F_IN + k0 + kq);
            xs[r][kq + 0] = xv.x; xs[r][kq + 1] = xv.y;
            xs[r][kq + 2] = xv.z; xs[r][kq + 3] = xv.w;
        }
        // stage W tile: 32 x 288 floats = 2304 float4s, 9 per thread
        #pragma unroll
        for (int j = 0; j < 9; ++j) {
            int idx = tid + j * 256;          // 0..2303
            int k  = idx / 72;                // 0..31
            int cq = (idx - k * 72) * 4;      // 0..284, 4-aligned, never crosses filter
            int ii = cq / F_OUT;
            int c  = cq - ii * F_OUT;
            float4 wv = *(const float4*)(w + (size_t)ii * (F_IN * F_OUT)
                                           + (size_t)(k0 + k) * F_OUT + c);
            ws[k][cq + 0] = wv.x; ws[k][cq + 1] = wv.y;
            ws[k][cq + 2] = wv.z; ws[k][cq + 3] = wv.w;
        }
        __syncthreads();
        #pragma unroll 8
        for (int kk = 0; kk < 32; ++kk) {
            float a[4], b[9];
            #pragma unroll
            for (int i = 0; i < 4; ++i) a[i] = xs[ty * 4 + i][kk];
            #pragma unroll
            for (int j = 0; j < 9; ++j) b[j] = ws[kk][tx * 9 + j];
            #pragma unroll
            for (int i = 0; i < 4; ++i)
                #pragma unroll
                for (int j = 0; j < 9; ++j)
                    acc[i][j] = fmaf(a[i], b[j], acc[i][j]);
        }
        __syncthreads();
    }
    // epilogue: apply first D multiply, write t
    #pragma unroll
    for (int i = 0; i < 4; ++i) {
        int m = m0 + ty * 4 + i;
        if (m >= N) continue;
        #pragma unroll
        for (int j = 0; j < 9; ++j) {
            int colg = tx * 9 + j;
            int ii = colg / F_OUT;
            t[(size_t)m * TCOLS + colg] = dsc[(size_t)ii * N + m] * acc[i][j];
        }
    }
}

// ---------------- fused SpMM + diagonal + relu + D + bias ----------------
// one block per row; thread f in [0,96) handles feature f for all 3 filters
__global__ __launch_bounds__(128) void spmm_kernel(const float* __restrict__ t,
                                                   const int* __restrict__ row_ptr,
                                                   const int* __restrict__ col_s,
                                                   const float* __restrict__ val_s,
                                                   const int* __restrict__ cnt,
                                                   const float* __restrict__ dsc,
                                                   const float* __restrict__ bias,
                                                   float* __restrict__ out, int N) {
    int n = blockIdx.x;
    int f = threadIdx.x;
    if (f >= F_OUT) return;
    int s = row_ptr[n], e = row_ptr[n + 1];
    float a0 = 0.f, a1 = 0.f, a2 = 0.f;
    for (int p = s; p < e; ++p) {
        int c = col_s[p];
        float v = val_s[p];
        const float* tr = t + (size_t)c * TCOLS;
        a0 = fmaf(v, tr[f], a0);
        a1 = fmaf(v, tr[F_OUT + f], a1);
        a2 = fmaf(v, tr[2 * F_OUT + f], a2);
    }
    float epsdi = EPSILON / (float)(cnt[n] + 1);   // deg includes self loop
    const float* tn = t + (size_t)n * TCOLS;
    float u0 = a0 - epsdi * tn[f];                 // filter 0: sign = -1
    float u1 = a1 + epsdi * tn[F_OUT + f];
    float u2 = a2 + epsdi * tn[2 * F_OUT + f];
    float r = fmaxf(u0, 0.f) * dsc[n]
            + fmaxf(u1, 0.f) * dsc[(size_t)N + n]
            + fmaxf(u2, 0.f) * dsc[2 * (size_t)N + n];
    out[(size_t)n * F_OUT + f] = r + bias[f];
}

extern "C" void kernel_launch(void* const* d_in, const int* in_sizes, int n_in,
                              void* d_out, int out_size, void* d_ws, size_t ws_size,
                              hipStream_t stream) {
    const float* x    = (const float*)d_in[0];
    const float* adj  = (const float*)d_in[1];
    const float* dsc  = (const float*)d_in[2];
    const float* w    = (const float*)d_in[3];
    const float* bias = (const float*)d_in[4];
    const int*   ei   = (const int*)d_in[5];

    int E = in_sizes[1];
    int N = in_sizes[0] / F_IN;
    const int* row = ei;
    const int* col = ei + E;
    float* out = (float*)d_out;

    // workspace carve-up (256B aligned)
    char* p = (char*)d_ws;
    auto take = [&](size_t bytes) {
        char* r = p;
        p += (bytes + 255) & ~(size_t)255;
        return r;
    };
    int*   cnt     = (int*)take((size_t)N * 4);
    int*   row_ptr = (int*)take((size_t)(N + 1) * 4);
    int*   offs    = (int*)take((size_t)N * 4);
    int*   bsums   = (int*)take(64 * 4);
    int*   col_s   = (int*)take((size_t)E * 4);
    float* val_s   = (float*)take((size_t)E * 4);
    float* t       = (float*)take((size_t)N * TCOLS * 4);  // 57.6 MB

    hipMemsetAsync(cnt, 0, (size_t)N * 4, stream);
    hist_kernel<<<(E + 255) / 256, 256, 0, stream>>>(row, cnt, E);
    int nb = (N + 1023) / 1024;   // 49 <= 64
    scan_part<<<nb, 256, 0, stream>>>(cnt, bsums, N);
    scan_sums<<<1, 64, 0, stream>>>(bsums, row_ptr, nb, E, N);
    scan_write<<<nb, 256, 0, stream>>>(cnt, bsums, row_ptr, offs, N);
    scatter_kernel<<<(E + 255) / 256, 256, 0, stream>>>(row, col, adj, offs, col_s, val_s, E);
    gemm_kernel<<<(N + 31) / 32, 256, 0, stream>>>(x, w, dsc, t, N);
    spmm_kernel<<<N, 128, 0, stream>>>(t, row_ptr, col_s, val_s, cnt, dsc, bias, out, N);
}

// Round 2
// 342.248 us; speedup vs baseline: 1.3093x; 1.3093x over previous
//
#include <hip/hip_runtime.h>

#define EPSILON 0.1f
#define F_IN 256
#define F_OUT 96
#define NF 3
#define TCOLS 288  // NF * F_OUT, t row layout: [n][ii*96 + f], bf16
#define LDA 40     // LDS leading dim (ushorts) for A tile: 16B-aligned rows, 2-way bank max
#define LDB 40

typedef __attribute__((ext_vector_type(8))) short bf8_t;   // 8 bf16 (4 VGPRs)
typedef __attribute__((ext_vector_type(4))) float f32x4;

__device__ inline ushort f2b(float f) {
    union { float f; unsigned u; } v; v.f = f;
    unsigned u = v.u;
    return (ushort)((u + 0x7FFFu + ((u >> 16) & 1u)) >> 16);  // RNE
}
__device__ inline float b2f(ushort h) {
    union { unsigned u; float f; } v; v.u = ((unsigned)h) << 16;
    return v.f;
}

// ---------------- histogram: edge counts per row ----------------
__global__ void hist_kernel(const int* __restrict__ row, int* __restrict__ cnt, int E) {
    int e = blockIdx.x * blockDim.x + threadIdx.x;
    if (e < E) atomicAdd(&cnt[row[e]], 1);
}

// ---------------- scan step 1: per-block (1024 elems) sums ----------------
__global__ __launch_bounds__(256) void scan_part(const int* __restrict__ cnt,
                                                 int* __restrict__ bsums, int N) {
    int i = blockIdx.x * 1024 + threadIdx.x * 4;
    int v = 0;
    if (i + 3 < N) {
        int4 q = *(const int4*)(cnt + i);
        v = q.x + q.y + q.z + q.w;
    } else {
        for (int j = 0; j < 4; ++j)
            if (i + j < N) v += cnt[i + j];
    }
    #pragma unroll
    for (int d = 32; d > 0; d >>= 1) v += __shfl_xor(v, d, 64);
    __shared__ int wsum[4];
    int lane = threadIdx.x & 63, wid = threadIdx.x >> 6;
    if (lane == 0) wsum[wid] = v;
    __syncthreads();
    if (threadIdx.x == 0) bsums[blockIdx.x] = wsum[0] + wsum[1] + wsum[2] + wsum[3];
}

// ---------------- scan step 2: exclusive scan of block sums (<=64 blocks) ----------------
__global__ void scan_sums(int* __restrict__ bsums, int* __restrict__ row_ptr,
                          int nb, int E, int N) {
    int lane = threadIdx.x;
    int v = (lane < nb) ? bsums[lane] : 0;
    int s = v;
    #pragma unroll
    for (int d = 1; d < 64; d <<= 1) {
        int o = __shfl_up(s, d, 64);
        if (lane >= d) s += o;
    }
    if (lane < nb) bsums[lane] = s - v;  // exclusive
    if (lane == 0) row_ptr[N] = E;
}

// ---------------- scan step 3: full exclusive scan, write row_ptr + offs ----------------
__global__ __launch_bounds__(256) void scan_write(const int* __restrict__ cnt,
                                                  const int* __restrict__ bsums,
                                                  int* __restrict__ row_ptr,
                                                  int* __restrict__ offs, int N) {
    int i = blockIdx.x * 1024 + threadIdx.x * 4;
    int q0 = 0, q1 = 0, q2 = 0, q3 = 0;
    if (i + 3 < N) {
        int4 q = *(const int4*)(cnt + i);
        q0 = q.x; q1 = q.y; q2 = q.z; q3 = q.w;
    } else {
        if (i     < N) q0 = cnt[i];
        if (i + 1 < N) q1 = cnt[i + 1];
        if (i + 2 < N) q2 = cnt[i + 2];
        if (i + 3 < N) q3 = cnt[i + 3];
    }
    int tsum = q0 + q1 + q2 + q3;
    int lane = threadIdx.x & 63, wid = threadIdx.x >> 6;
    int s = tsum;
    #pragma unroll
    for (int d = 1; d < 64; d <<= 1) {
        int o = __shfl_up(s, d, 64);
        if (lane >= d) s += o;
    }
    __shared__ int wsum[4];
    if (lane == 63) wsum[wid] = s;
    __syncthreads();
    int woff = 0;
    for (int w = 0; w < wid; ++w) woff += wsum[w];
    int e0 = bsums[blockIdx.x] + woff + (s - tsum);
    if (i     < N) { row_ptr[i]     = e0; offs[i]     = e0; } e0 += q0;
    if (i + 1 < N) { row_ptr[i + 1] = e0; offs[i + 1] = e0; } e0 += q1;
    if (i + 2 < N) { row_ptr[i + 2] = e0; offs[i + 2] = e0; } e0 += q2;
    if (i + 3 < N) { row_ptr[i + 3] = e0; offs[i + 3] = e0; }
}

// ---------------- scatter edges into CSR order ----------------
__global__ void scatter_kernel(const int* __restrict__ row, const int* __restrict__ col,
                               const float* __restrict__ vals, int* __restrict__ offs,
                               int* __restrict__ col_s, float* __restrict__ val_s, int E) {
    int e = blockIdx.x * blockDim.x + threadIdx.x;
    if (e < E) {
        int r = row[e];
        int p = atomicAdd(&offs[r], 1);
        col_s[p] = col[e];
        val_s[p] = vals[e];
    }
}

// ---------------- W convert+transpose: wt[gc][k] = bf16(w[ii][k][f]), gc = ii*96+f ----------------
__global__ void cvt_w(const float* __restrict__ w, ushort* __restrict__ wt) {
    int idx = blockIdx.x * 256 + threadIdx.x;   // < 288*256
    if (idx >= TCOLS * F_IN) return;
    int gc = idx >> 8;          // 0..287
    int k  = idx & 255;
    int ii = gc / F_OUT;
    int c  = gc - ii * F_OUT;
    wt[idx] = f2b(w[(size_t)ii * (F_IN * F_OUT) + (size_t)k * F_OUT + c]);
}

// ---------------- MFMA GEMM: t[n][288] = bf16( dsc[ii][n] * (x @ W[ii])[n][f] ) ----------------
// BM=64 rows, BN=288 (all filters), block=256 (4 waves x 16 rows), 16x16x32 bf16 mfma.
// fp32->bf16 conversion fused into A staging; B pre-transposed to [gc][k] by cvt_w.
__global__ __launch_bounds__(256) void gemm_mfma(const float* __restrict__ x,
                                                 const ushort* __restrict__ wt,
                                                 const float* __restrict__ dsc,
                                                 ushort* __restrict__ t, int N) {
    __shared__ ushort As[64 * LDA];
    __shared__ ushort Bs[TCOLS * LDB];

    int tid = threadIdx.x;
    int lane = tid & 63, wave = tid >> 6;
    int m0 = blockIdx.x * 64;

    f32x4 acc[18];
    #pragma unroll
    for (int j = 0; j < 18; ++j) acc[j] = (f32x4){0.f, 0.f, 0.f, 0.f};

    int arow = wave * 16 + (lane & 15);
    int koff = (lane >> 4) * 8;      // 0,8,16,24

    for (int k0 = 0; k0 < F_IN; k0 += 32) {
        // stage A: 64x32 fp32 -> bf16 LDS, 2 float4 per thread
        #pragma unroll
        for (int it = 0; it < 2; ++it) {
            int idx = tid + it * 256;         // 0..511
            int r = idx >> 3;                 // 0..63
            int kq = (idx & 7) * 4;           // 0..28
            float4 xv = make_float4(0.f, 0.f, 0.f, 0.f);
            if (m0 + r < N)
                xv = *(const float4*)(x + (size_t)(m0 + r) * F_IN + k0 + kq);
            ushort* d = As + r * LDA + kq;
            d[0] = f2b(xv.x); d[1] = f2b(xv.y); d[2] = f2b(xv.z); d[3] = f2b(xv.w);
        }
        // stage B: 288 x 32 bf16 (from wt[gc][k]), 16B chunks
        #pragma unroll
        for (int j = 0; j < 5; ++j) {
            int idx = tid + j * 256;          // 0..1279
            if (idx < TCOLS * 4) {
                int gc = idx >> 2;            // 0..287
                int ch = (idx & 3) * 8;       // ushort offset, 16B chunks
                *(uint4*)(Bs + gc * LDB + ch) =
                    *(const uint4*)(wt + (size_t)gc * F_IN + k0 + ch);
            }
        }
        __syncthreads();
        bf8_t a = *(const bf8_t*)(As + arow * LDA + koff);
        #pragma unroll
        for (int j = 0; j < 18; ++j) {
            bf8_t b = *(const bf8_t*)(Bs + (j * 16 + (lane & 15)) * LDB + koff);
            acc[j] = __builtin_amdgcn_mfma_f32_16x16x32_bf16(a, b, acc[j], 0, 0, 0);
        }
        __syncthreads();
    }

    // epilogue: C/D layout col=lane&15, row=(lane>>4)*4+reg
    int rowb = m0 + wave * 16 + (lane >> 4) * 4;
    float dscv[3][4];
    #pragma unroll
    for (int ii = 0; ii < 3; ++ii)
        #pragma unroll
        for (int r = 0; r < 4; ++r) {
            int row = rowb + r;
            dscv[ii][r] = (row < N) ? dsc[(size_t)ii * N + row] : 0.f;
        }
    #pragma unroll
    for (int j = 0; j < 18; ++j) {
        int gc = j * 16 + (lane & 15);
        int ii = j / 6;                       // 96 = 6 tiles of 16
        #pragma unroll
        for (int r = 0; r < 4; ++r) {
            int row = rowb + r;
            if (row < N)
                t[(size_t)row * TCOLS + gc] = f2b(dscv[ii][r] * acc[j][r]);
        }
    }
}

// ---------------- fused SpMM + diagonal + relu + D + bias (t in bf16) ----------------
__global__ __launch_bounds__(128) void spmm_kernel(const ushort* __restrict__ t,
                                                   const int* __restrict__ row_ptr,
                                                   const int* __restrict__ col_s,
                                                   const float* __restrict__ val_s,
                                                   const int* __restrict__ cnt,
                                                   const float* __restrict__ dsc,
                                                   const float* __restrict__ bias,
                                                   float* __restrict__ out, int N) {
    int n = blockIdx.x;
    int f = threadIdx.x;
    if (f >= F_OUT) return;
    int s = row_ptr[n], e = row_ptr[n + 1];
    float a0 = 0.f, a1 = 0.f, a2 = 0.f;
    for (int p = s; p < e; ++p) {
        int c = col_s[p];
        float v = val_s[p];
        const ushort* tr = t + (size_t)c * TCOLS;
        a0 = fmaf(v, b2f(tr[f]), a0);
        a1 = fmaf(v, b2f(tr[F_OUT + f]), a1);
        a2 = fmaf(v, b2f(tr[2 * F_OUT + f]), a2);
    }
    float epsdi = EPSILON / (float)(cnt[n] + 1);   // deg includes self loop
    const ushort* tn = t + (size_t)n * TCOLS;
    float u0 = a0 - epsdi * b2f(tn[f]);            // filter 0: sign = -1
    float u1 = a1 + epsdi * b2f(tn[F_OUT + f]);
    float u2 = a2 + epsdi * b2f(tn[2 * F_OUT + f]);
    float r = fmaxf(u0, 0.f) * dsc[n]
            + fmaxf(u1, 0.f) * dsc[(size_t)N + n]
            + fmaxf(u2, 0.f) * dsc[2 * (size_t)N + n];
    out[(size_t)n * F_OUT + f] = r + bias[f];
}

extern "C" void kernel_launch(void* const* d_in, const int* in_sizes, int n_in,
                              void* d_out, int out_size, void* d_ws, size_t ws_size,
                              hipStream_t stream) {
    const float* x    = (const float*)d_in[0];
    const float* adj  = (const float*)d_in[1];
    const float* dsc  = (const float*)d_in[2];
    const float* w    = (const float*)d_in[3];
    const float* bias = (const float*)d_in[4];
    const int*   ei   = (const int*)d_in[5];

    int E = in_sizes[1];
    int N = in_sizes[0] / F_IN;
    const int* row = ei;
    const int* col = ei + E;
    float* out = (float*)d_out;

    // workspace carve-up (256B aligned)
    char* p = (char*)d_ws;
    auto take = [&](size_t bytes) {
        char* r = p;
        p += (bytes + 255) & ~(size_t)255;
        return r;
    };
    int*    cnt     = (int*)take((size_t)N * 4);
    int*    row_ptr = (int*)take((size_t)(N + 1) * 4);
    int*    offs    = (int*)take((size_t)N * 4);
    int*    bsums   = (int*)take(64 * 4);
    int*    col_s   = (int*)take((size_t)E * 4);
    float*  val_s   = (float*)take((size_t)E * 4);
    ushort* wt      = (ushort*)take((size_t)TCOLS * F_IN * 2);
    ushort* t       = (ushort*)take((size_t)N * TCOLS * 2);   // 28.8 MB bf16

    hipMemsetAsync(cnt, 0, (size_t)N * 4, stream);
    cvt_w<<<(TCOLS * F_IN + 255) / 256, 256, 0, stream>>>(w, wt);
    hist_kernel<<<(E + 255) / 256, 256, 0, stream>>>(row, cnt, E);
    int nb = (N + 1023) / 1024;   // 49 <= 64
    scan_part<<<nb, 256, 0, stream>>>(cnt, bsums, N);
    scan_sums<<<1, 64, 0, stream>>>(bsums, row_ptr, nb, E, N);
    scan_write<<<nb, 256, 0, stream>>>(cnt, bsums, row_ptr, offs, N);
    scatter_kernel<<<(E + 255) / 256, 256, 0, stream>>>(row, col, adj, offs, col_s, val_s, E);
    gemm_mfma<<<(N + 63) / 64, 256, 0, stream>>>(x, wt, dsc, t, N);
    spmm_kernel<<<N, 128, 0, stream>>>(t, row_ptr, col_s, val_s, cnt, dsc, bias, out, N);
}